// Round 1
// 353.264 us; speedup vs baseline: 1.0596x; 1.0596x over previous
//
#include <hip/hip_runtime.h>
#include <hip/hip_bf16.h>

#define HW    16384   // 128*128
#define IMW   128
#define IMH   128
#define CIN   256
#define CR    64
#define G     16
#define GC    16

typedef __attribute__((ext_vector_type(8))) short short8;
typedef __attribute__((ext_vector_type(4))) float floatx4;

static __device__ __forceinline__ short f2bf(float f) {
  union { float f; unsigned u; } v; v.f = f;
  unsigned r = v.u + 0x7fffu + ((v.u >> 16) & 1u);   // RNE
  return (short)(r >> 16);
}
static __device__ __forceinline__ float bf2f(short s) {
  union { unsigned u; float f; } v; v.u = ((unsigned)(unsigned short)s) << 16;
  return v.f;
}

// ---------------------------------------------------------------------------
// K0: convert w1 (fp32 [64][256]) -> bf16, row-major. 64 blocks x 256.
// ---------------------------------------------------------------------------
__global__ __launch_bounds__(256) void k_cvt_w1(const float* __restrict__ w1,
                                                short* __restrict__ w1b) {
  const int i = blockIdx.x * 256 + threadIdx.x;      // 16384 elements
  w1b[i] = f2bf(w1[i]);
}

// ---------------------------------------------------------------------------
// K1: 1x1 conv 256->64 as bf16 MFMA GEMM: y1 = w1[64x256] * x[256xHW].
// Block 256 = 4 waves; wave handles 16 pixels x all 64 outputs (4 M-tiles,
// 16x16x32 MFMA). K-loop unrolled by 2 (two independent load sets issued
// up front -> 24 loads in flight per wave instead of 12).
// Grid: 8 * 256 = 2048 blocks.
// ---------------------------------------------------------------------------
__global__ __launch_bounds__(256) void k_conv1_mfma(const float* __restrict__ x,
                                                    const short* __restrict__ w1b,
                                                    const float* __restrict__ b1,
                                                    short* __restrict__ y1b) {
  const int blk  = blockIdx.x;          // b*256 + pixel-tile
  const int b    = blk >> 8;
  const int pt   = blk & 255;
  const int wave = threadIdx.x >> 6;
  const int lane = threadIdx.x & 63;
  const int quad = lane >> 4;
  const int l16  = lane & 15;
  const int p    = pt * 64 + wave * 16 + l16;

  const float* xb = x + (size_t)b * CIN * HW + p;

  floatx4 acc[4];
#pragma unroll
  for (int mt = 0; mt < 4; ++mt)
#pragma unroll
    for (int r = 0; r < 4; ++r) acc[mt][r] = b1[mt * 16 + quad * 4 + r];

#pragma unroll 1
  for (int kk = 0; kk < CIN; kk += 64) {
    // ---- issue ALL loads for both k-substeps first (MLP) ----
    short8 af0[4], af1[4];
#pragma unroll
    for (int mt = 0; mt < 4; ++mt) {
      af0[mt] = *(const short8*)(w1b + (mt * 16 + l16) * CIN + kk + quad * 8);
      af1[mt] = *(const short8*)(w1b + (mt * 16 + l16) * CIN + kk + 32 + quad * 8);
    }
    float xv0[8], xv1[8];
#pragma unroll
    for (int j = 0; j < 8; ++j)
      xv0[j] = xb[(size_t)(kk + quad * 8 + j) * HW];
#pragma unroll
    for (int j = 0; j < 8; ++j)
      xv1[j] = xb[(size_t)(kk + 32 + quad * 8 + j) * HW];

    short8 bf0, bf1;
#pragma unroll
    for (int j = 0; j < 8; ++j) bf0[j] = f2bf(xv0[j]);
#pragma unroll
    for (int j = 0; j < 8; ++j) bf1[j] = f2bf(xv1[j]);

#pragma unroll
    for (int mt = 0; mt < 4; ++mt)
      acc[mt] = __builtin_amdgcn_mfma_f32_16x16x32_bf16(af0[mt], bf0, acc[mt], 0, 0, 0);
#pragma unroll
    for (int mt = 0; mt < 4; ++mt)
      acc[mt] = __builtin_amdgcn_mfma_f32_16x16x32_bf16(af1[mt], bf1, acc[mt], 0, 0, 0);
  }

  short* yb = y1b + (size_t)b * CR * HW + p;
#pragma unroll
  for (int mt = 0; mt < 4; ++mt)
#pragma unroll
    for (int r = 0; r < 4; ++r)
      yb[(size_t)(mt * 16 + quad * 4 + r) * HW] = f2bf(acc[mt][r]);
}

// ---------------------------------------------------------------------------
// K2: depthwise 3x3 over y1b (bf16 in/out), zero pad 1. Vectorized rewrite:
// thread = 2 rows x 8 cols (short8 loads/stores). Block: 256 threads cover
// 32 rows x 128 cols of one (b,c) plane. Grid: 8 * 64 * 4 = 2048.
// Per thread: 4x short8 + 8 scalar loads -> 16 outputs (vs 18 loads / 4 before).
// ---------------------------------------------------------------------------
__global__ __launch_bounds__(256) void k_dw(const short* __restrict__ y1b,
                                            const float* __restrict__ wd,
                                            const float* __restrict__ bd,
                                            short* __restrict__ y2b) {
  const int blk   = blockIdx.x;         // ((b*64 + c)*4 + strip)
  const int strip = blk & 3;
  const int c     = (blk >> 2) & 63;
  const int b     = blk >> 8;
  const int tcol  = threadIdx.x & 15;   // 16 thread-cols * 8 px
  const int trow  = threadIdx.x >> 4;   // 16 thread-rows * 2 rows
  const int r0    = strip * 32 + trow * 2;
  const int c0    = tcol * 8;

  const short* src = y1b + (size_t)(b * CR + c) * HW;

  const float mcl = c0 > 0 ? 1.f : 0.f;
  const float mcr = c0 + 8 < IMW ? 1.f : 0.f;
  const int   cl  = c0 > 0 ? c0 - 1 : 0;
  const int   crr = c0 + 8 < IMW ? c0 + 8 : IMW - 1;

  float f[4][10];
#pragma unroll
  for (int i = 0; i < 4; ++i) {
    const int rr = r0 - 1 + i;
    const int rc = rr < 0 ? 0 : (rr > IMH - 1 ? IMH - 1 : rr);
    const float mr = (rr < 0 || rr > IMH - 1) ? 0.f : 1.f;
    const short* row = src + rc * IMW;
    const short8 v = *(const short8*)(row + c0);
#pragma unroll
    for (int j = 0; j < 8; ++j) f[i][j + 1] = mr * bf2f(v[j]);
    f[i][0] = mr * mcl * bf2f(row[cl]);
    f[i][9] = mr * mcr * bf2f(row[crr]);
  }

  float wv[9];
#pragma unroll
  for (int j = 0; j < 9; ++j) wv[j] = wd[c * 9 + j];
  const float bias = bd[c];

  short* dst = y2b + (size_t)(b * CR + c) * HW + r0 * IMW + c0;
#pragma unroll
  for (int i = 0; i < 2; ++i) {
    short8 o;
#pragma unroll
    for (int xcol = 0; xcol < 8; ++xcol) {
      float acc = bias;
#pragma unroll
      for (int kh = 0; kh < 3; ++kh)
#pragma unroll
        for (int kw = 0; kw < 3; ++kw)
          acc += wv[kh * 3 + kw] * f[i + kh][xcol + kw];
      o[xcol] = f2bf(acc);
    }
    *(short8*)(dst + i * IMW) = o;
  }
}

// ---------------------------------------------------------------------------
// K3: fused conv2 (64->144) + involution. No LDS, no barriers.
// Retiled 16x16 -> 8x32: y2 row reads are full 64B lines, x tap reads are
// 128B wave segments. Block: 256 threads = one 8x32 pixel tile, 2 groups.
// Grid: B * 8 * 64 = 4096 blocks (8 gp-blocks per tile stay on one XCD:
// delta-blk = 64 == 0 mod 8 -> y2 tile L2-resident across the 8 readers).
// ---------------------------------------------------------------------------
__global__ __launch_bounds__(256) void k_conv2invol(const float* __restrict__ x,
                                                    const short* __restrict__ y2b,
                                                    const float* __restrict__ w2,
                                                    const float* __restrict__ b2,
                                                    float* __restrict__ out) {
  const int blk  = blockIdx.x;         // (b*8 + gp)*64 + tile
  const int tile = blk & 63;           // 16 row-tiles x 4 col-tiles
  const int gp   = (blk >> 6) & 7;
  const int b    = blk >> 9;
  const int g0   = gp * 2;
  const int tid  = threadIdx.x;
  const int tr   = tid >> 5;           // 0..7
  const int tc   = tid & 31;           // 0..31
  const int h    = (tile >> 2) * 8 + tr;
  const int w    = (tile & 3) * 32 + tc;
  const int p    = h * IMW + w;

  // ---- phase 1: dynamic weights for this pixel, groups g0, g0+1 ----
  float wv[2][9];
#pragma unroll
  for (int q = 0; q < 2; ++q)
#pragma unroll
    for (int j = 0; j < 9; ++j) wv[q][j] = b2[(g0 + q) * 9 + j];

  const short* y2p = y2b + (size_t)b * CR * HW + p;
#pragma unroll 2
  for (int c = 0; c < CR; c += 4) {
    const float v0 = bf2f(y2p[(size_t)(c + 0) * HW]);
    const float v1 = bf2f(y2p[(size_t)(c + 1) * HW]);
    const float v2 = bf2f(y2p[(size_t)(c + 2) * HW]);
    const float v3 = bf2f(y2p[(size_t)(c + 3) * HW]);
#pragma unroll
    for (int q = 0; q < 2; ++q)
#pragma unroll
      for (int j = 0; j < 9; ++j) {
        const float4 wq = *(const float4*)(w2 + ((g0 + q) * 9 + j) * CR + c); // uniform
        wv[q][j] += wq.x * v0 + wq.y * v1 + wq.z * v2 + wq.w * v3;
      }
  }

  // ---- fold borders into weights; clamped tap offsets ----
  const int   hcl[3] = {h > 0 ? h - 1 : 0, h, h < IMH - 1 ? h + 1 : IMH - 1};
  const int   wcl[3] = {w > 0 ? w - 1 : 0, w, w < IMW - 1 ? w + 1 : IMW - 1};
  const float mr[3]  = {h > 0 ? 1.f : 0.f, 1.f, h < IMH - 1 ? 1.f : 0.f};
  const float mc[3]  = {w > 0 ? 1.f : 0.f, 1.f, w < IMW - 1 ? 1.f : 0.f};
  int rel[9];
#pragma unroll
  for (int kh = 0; kh < 3; ++kh)
#pragma unroll
    for (int kw = 0; kw < 3; ++kw) {
      rel[kh * 3 + kw] = hcl[kh] * IMW + wcl[kw];
      const float m = mr[kh] * mc[kw];
      wv[0][kh * 3 + kw] *= m;
      wv[1][kh * 3 + kw] *= m;
    }

  // ---- phase 2: involution, branchless taps through L1 ----
  const float* xb = x + (size_t)b * CIN * HW;
  float*       ob = out + (size_t)b * CIN * HW;

#pragma unroll
  for (int q = 0; q < 2; ++q) {
#pragma unroll 4
    for (int cc = 0; cc < GC; ++cc) {
      const int ch = (g0 + q) * GC + cc;
      const float* xp = xb + (size_t)ch * HW;
      float acc = 0.f;
#pragma unroll
      for (int j = 0; j < 9; ++j) acc += wv[q][j] * xp[rel[j]];
      ob[(size_t)ch * HW + p] = acc;
    }
  }
}

extern "C" void kernel_launch(void* const* d_in, const int* in_sizes, int n_in,
                              void* d_out, int out_size, void* d_ws, size_t ws_size,
                              hipStream_t stream) {
  const float* x  = (const float*)d_in[0];
  const float* w1 = (const float*)d_in[1];
  const float* b1 = (const float*)d_in[2];
  const float* wd = (const float*)d_in[3];
  const float* bd = (const float*)d_in[4];
  const float* w2 = (const float*)d_in[5];
  const float* b2 = (const float*)d_in[6];
  float* out = (float*)d_out;

  // ws layout: w1b bf16 (32 KB, padded to 64 KB) | y1b bf16 16.7 MB | y2b bf16 16.7 MB
  short* w1b = (short*)d_ws;
  short* y1b = (short*)((char*)d_ws + 65536);
  short* y2b = y1b + (size_t)8 * CR * HW;

  k_cvt_w1<<<dim3(64), dim3(256), 0, stream>>>(w1, w1b);
  k_conv1_mfma<<<dim3(2048), dim3(256), 0, stream>>>(x, w1b, b1, y1b);
  k_dw<<<dim3(2048), dim3(256), 0, stream>>>(y1b, wd, bd, y2b);
  k_conv2invol<<<dim3(4096), dim3(256), 0, stream>>>(x, y2b, w2, b2, out);
}